// Round 1
// baseline (281.074 us; speedup 1.0000x reference)
//
#include <hip/hip_runtime.h>
#include <hip/hip_bf16.h>

#define TOKEN_DIM 16
#define RANGES 5
#define MAX_RS 20000    // + DUMMY floats -> 80128 B LDS/block -> 2 blocks/CU
#define DUMMY  32
#define MAX_C  96       // multiple of 8: every XCD owns exactly C/8 chunks
#define NXCD   8

// Phase 1: block (chunk c, range r) scans edge chunk c, accumulates
// s[row] += x[col] for rows in its range via LDS atomics, writes its
// partial slice (bf16, non-temporal).
//
// This round:
//  * XCD co-location: blockIdx%8 == c%8, so all RANGES blocks of one chunk
//    run on the SAME XCD and share its L2 copy of the 533 KB edge chunk
//    (was: 5 different XCDs -> 5x L3/HBM re-read, FETCH_SIZE 126 MB).
//  * Branch-free inner loop: 8 gathers issued unconditionally (inactive
//    lanes clamped to x[0], a broadcast), then 8 unconditional ds_adds
//    (inactive lanes -> per-lane dummy slot, v=0). Turns 8 serialized
//    load->waitcnt->atomic chains per iteration into one load batch.
__global__ __launch_bounds__(1024, 8)
void nit_phase1(const int* __restrict__ row, const int* __restrict__ col,
                const float* __restrict__ x,
                unsigned short* __restrict__ partial,   // [C][N] bf16 bits
                int N, long long E, int chunkE, int RS, int C) {
    __shared__ float acc[MAX_RS + DUMMY];
    const int b = blockIdx.x;
    const int k = b % NXCD;                 // physical XCD (round-robin heuristic)
    const int s = b / NXCD;                 // slot within this XCD
    const int r = s % RANGES;
    const int c = k + NXCD * (s / RANGES);  // chunk: c % 8 == k
    if (c >= C) return;                     // block-uniform, before any barrier

    const int base = r * RS;
    int cnt = N - base; if (cnt > RS) cnt = RS; if (cnt < 0) cnt = 0;
    const int t = threadIdx.x, nt = blockDim.x;

    for (int j = t; j < cnt; j += nt) acc[j] = 0.0f;
    if (t < DUMMY) acc[RS + t] = 0.0f;
    __syncthreads();

    long long i0 = (long long)c * chunkE;
    long long i1 = i0 + chunkE; if (i1 > E) i1 = E;
    long long len = (i1 > i0) ? (i1 - i0) : 0;
    long long ngrp = len >> 3;              // 8 edges/group (i0 is 8-aligned)
    const unsigned ucnt = (unsigned)cnt;
    const int dummy = RS + (t & (DUMMY - 1));

    for (long long g = t; g < ngrp; g += nt) {
        const long long idx = i0 + (g << 3);
        const int4 r0 = *reinterpret_cast<const int4*>(row + idx);
        const int4 r1 = *reinterpret_cast<const int4*>(row + idx + 4);
        const int4 c0 = *reinterpret_cast<const int4*>(col + idx);
        const int4 c1 = *reinterpret_cast<const int4*>(col + idx + 4);

        const unsigned d0 = (unsigned)(r0.x - base);
        const unsigned d1 = (unsigned)(r0.y - base);
        const unsigned d2 = (unsigned)(r0.z - base);
        const unsigned d3 = (unsigned)(r0.w - base);
        const unsigned d4 = (unsigned)(r1.x - base);
        const unsigned d5 = (unsigned)(r1.y - base);
        const unsigned d6 = (unsigned)(r1.z - base);
        const unsigned d7 = (unsigned)(r1.w - base);

        // batched gathers: all issued before any consumer waitcnt
        const float v0 = x[d0 < ucnt ? c0.x : 0];
        const float v1 = x[d1 < ucnt ? c0.y : 0];
        const float v2 = x[d2 < ucnt ? c0.z : 0];
        const float v3 = x[d3 < ucnt ? c0.w : 0];
        const float v4 = x[d4 < ucnt ? c1.x : 0];
        const float v5 = x[d5 < ucnt ? c1.y : 0];
        const float v6 = x[d6 < ucnt ? c1.z : 0];
        const float v7 = x[d7 < ucnt ? c1.w : 0];

        // unconditional atomics: out-of-range lanes add 0.0 to a dummy slot
        atomicAdd(&acc[d0 < ucnt ? (int)d0 : dummy], d0 < ucnt ? v0 : 0.0f);
        atomicAdd(&acc[d1 < ucnt ? (int)d1 : dummy], d1 < ucnt ? v1 : 0.0f);
        atomicAdd(&acc[d2 < ucnt ? (int)d2 : dummy], d2 < ucnt ? v2 : 0.0f);
        atomicAdd(&acc[d3 < ucnt ? (int)d3 : dummy], d3 < ucnt ? v3 : 0.0f);
        atomicAdd(&acc[d4 < ucnt ? (int)d4 : dummy], d4 < ucnt ? v4 : 0.0f);
        atomicAdd(&acc[d5 < ucnt ? (int)d5 : dummy], d5 < ucnt ? v5 : 0.0f);
        atomicAdd(&acc[d6 < ucnt ? (int)d6 : dummy], d6 < ucnt ? v6 : 0.0f);
        atomicAdd(&acc[d7 < ucnt ? (int)d7 : dummy], d7 < ucnt ? v7 : 0.0f);
    }
    for (long long idx = i0 + (ngrp << 3) + t; idx < i1; idx += nt) {
        unsigned d = (unsigned)(row[idx] - base);
        if (d < ucnt) atomicAdd(&acc[d], x[col[idx]]);
    }
    __syncthreads();

    unsigned short* dst = partial + (size_t)c * N + base;
    const bool vec_ok = ((((size_t)c * N + base) & 1) == 0);
    if (vec_ok) {
        const int cnt2 = cnt >> 1;
        unsigned int* dst2 = reinterpret_cast<unsigned int*>(dst);
        for (int j = t; j < cnt2; j += nt) {
            __hip_bfloat16 ha = __float2bfloat16(acc[2 * j]);
            __hip_bfloat16 hb = __float2bfloat16(acc[2 * j + 1]);
            unsigned int w = (unsigned int)(*reinterpret_cast<unsigned short*>(&ha))
                           | ((unsigned int)(*reinterpret_cast<unsigned short*>(&hb)) << 16);
            __builtin_nontemporal_store(w, dst2 + j);
        }
        if ((cnt & 1) && t == 0) {
            __hip_bfloat16 h = __float2bfloat16(acc[cnt - 1]);
            __builtin_nontemporal_store(*reinterpret_cast<unsigned short*>(&h), dst + cnt - 1);
        }
    } else {
        for (int j = t; j < cnt; j += nt) {
            __hip_bfloat16 h = __float2bfloat16(acc[j]);
            __builtin_nontemporal_store(*reinterpret_cast<unsigned short*>(&h), dst + j);
        }
    }
}

// Phase 2: 64-node tile per block; C-chunk reduction split across 4 waves'
// worth of threads (coalesced bf16 streams), LDS-reduced, then 64 threads
// run the 2->16->16 MLP.
__global__ __launch_bounds__(256, 8)
void nit_phase2(const float* __restrict__ x,
                const unsigned short* __restrict__ partial,
                const float* __restrict__ w1, const float* __restrict__ b1,
                const float* __restrict__ w2, const float* __restrict__ b2,
                float* __restrict__ out, int N, int C) {
    __shared__ float sw1[TOKEN_DIM * 2];
    __shared__ float sb1[TOKEN_DIM];
    __shared__ float sw2[TOKEN_DIM * TOKEN_DIM];
    __shared__ float sb2[TOKEN_DIM];
    __shared__ float red[256];

    const int t = threadIdx.x;
    if (t < TOKEN_DIM * TOKEN_DIM) sw2[t] = w2[t];
    if (t < TOKEN_DIM * 2) sw1[t] = w1[t];
    if (t < TOKEN_DIM) { sb1[t] = b1[t]; sb2[t] = b2[t]; }

    const int n = t & 63;
    const int g = t >> 6;
    const int node0 = blockIdx.x * 64;
    const int node = node0 + n;

    float s = 0.0f;
    if (node < N) {
#pragma unroll 4
        for (int c = g; c < C; c += 4) {
            unsigned short u = __builtin_nontemporal_load(partial + (size_t)c * N + node);
            s += __uint_as_float(((unsigned)u) << 16);   // bf16 -> f32
        }
    }
    red[t] = s;
    __syncthreads();

    if (t < 64) {
        const int nn = node0 + t;
        if (nn < N) {
            const float ssum = red[t] + red[64 + t] + red[128 + t] + red[192 + t];
            const float xv = x[nn];
            const float lv = xv * ssum;

            float h[TOKEN_DIM];
#pragma unroll
            for (int j = 0; j < TOKEN_DIM; ++j) {
                float v = fmaf(xv, sw1[2 * j], fmaf(lv, sw1[2 * j + 1], sb1[j]));
                h[j] = v > 0.0f ? v : 0.0f;
            }

            float o[TOKEN_DIM];
#pragma unroll
            for (int j = 0; j < TOKEN_DIM; ++j) {
                float v = sb2[j];
#pragma unroll
                for (int k = 0; k < TOKEN_DIM; ++k)
                    v = fmaf(h[k], sw2[j * TOKEN_DIM + k], v);
                o[j] = v > 0.0f ? v : 0.0f;
            }

            float4* op = reinterpret_cast<float4*>(out + (size_t)nn * TOKEN_DIM);
#pragma unroll
            for (int j = 0; j < 4; ++j)
                op[j] = make_float4(o[4 * j], o[4 * j + 1], o[4 * j + 2], o[4 * j + 3]);
        }
    }
}

extern "C" void kernel_launch(void* const* d_in, const int* in_sizes, int n_in,
                              void* d_out, int out_size, void* d_ws, size_t ws_size,
                              hipStream_t stream) {
    const float* x  = (const float*)d_in[0];
    const int*   ei = (const int*)d_in[1];   // [2, E] flat: rows then cols
    const float* w1 = (const float*)d_in[2];
    const float* b1 = (const float*)d_in[3];
    const float* w2 = (const float*)d_in[4];
    const float* b2 = (const float*)d_in[5];
    float* out = (float*)d_out;

    const int N = in_sizes[0];
    const long long E = in_sizes[1] / 2;
    const int* row = ei;
    const int* col = ei + E;

    // partials are [C][N] bf16 (2 B each), bounded by workspace capacity
    long long maxC = (long long)(ws_size / ((size_t)N * sizeof(unsigned short)));
    int C = maxC < 1 ? 1 : (maxC > MAX_C ? MAX_C : (int)maxC);
    int RS = ((N + RANGES - 1) / RANGES + 1) & ~1;   // even so bf16 slices stay 4B-aligned
    long long ce = (E + C - 1) / C;
    int chunkE = (int)((ce + 7LL) & ~7LL);           // 8-aligned for int4 group loads

    unsigned short* partial = (unsigned short*)d_ws;

    const int cg = (C + NXCD - 1) / NXCD;
    const int grid1 = NXCD * RANGES * cg;            // 480 for C=96
    nit_phase1<<<grid1, 1024, 0, stream>>>(row, col, x, partial,
                                           N, E, chunkE, RS, C);

    int grid2 = (N + 63) / 64;
    nit_phase2<<<grid2, 256, 0, stream>>>(x, partial, w1, b1, w2, b2,
                                          out, N, C);
}